// Round 1
// baseline (85.865 us; speedup 1.0000x reference)
//
#include <hip/hip_runtime.h>
#include <hip/hip_bf16.h>

#define NPTS 8192
#define NB   4
#define BLK  256
#define QPT  4                   // queries per thread
#define QPB  (QPT * BLK)         // 1024 queries per block
#define NQC  (NPTS / QPB)        // 8 query chunks
#define SS   8                   // search slices
#define SPS  (NPTS / SS)         // 1024 search points per slice
#define THR  3.33f

__device__ __forceinline__ unsigned enc_f(float f) {
    unsigned u = __float_as_uint(f);
    return (u & 0x80000000u) ? ~u : (u | 0x80000000u);
}
__device__ __forceinline__ float dec_f(unsigned u) {
    return (u & 0x80000000u) ? __uint_as_float(u & 0x7FFFFFFFu)
                             : __uint_as_float(~u);
}

// Kernel 1: for each (batch, dir, query), compute max over search slice of
// t = 2*q.s - |s|^2 ; combine slices via atomicMax on monotone-encoded uint.
__global__ __launch_bounds__(BLK) void knn_max_kernel(
    const float* __restrict__ Ps, const float* __restrict__ Pd,
    const float* __restrict__ F,  const int* __restrict__ Ms,
    const int* __restrict__ Md,   unsigned* __restrict__ best)
{
    const int b   = blockIdx.z;
    const int dir = blockIdx.y;
    const int qc  = blockIdx.x / SS;
    const int sl  = blockIdx.x % SS;
    const int tid = threadIdx.x;
    const int base = b * NPTS;

    __shared__ float4 sp[SPS];

    // stage search points: dir0 -> dst (valid_d), dir1 -> warped src (valid_s)
    for (int i = tid; i < SPS; i += BLK) {
        const int g = base + sl * SPS + i;
        float x, y, z; int v;
        if (dir == 0) {
            x = Pd[g * 3 + 0]; y = Pd[g * 3 + 1]; z = Pd[g * 3 + 2];
            v = Md[g];
        } else {
            x = Ps[g * 3 + 0] + F[g * 3 + 0];
            y = Ps[g * 3 + 1] + F[g * 3 + 1];
            z = Ps[g * 3 + 2] + F[g * 3 + 2];
            v = Ms[g];
        }
        if (v > 0)
            sp[i] = make_float4(2.f * x, 2.f * y, 2.f * z, -(x * x + y * y + z * z));
        else
            sp[i] = make_float4(0.f, 0.f, 0.f, -1e30f);
    }
    __syncthreads();

    // load queries: dir0 -> warped src, dir1 -> dst
    float qx[QPT], qy[QPT], qz[QPT], bt[QPT];
#pragma unroll
    for (int k = 0; k < QPT; ++k) {
        const int g = base + qc * QPB + k * BLK + tid;
        if (dir == 0) {
            qx[k] = Ps[g * 3 + 0] + F[g * 3 + 0];
            qy[k] = Ps[g * 3 + 1] + F[g * 3 + 1];
            qz[k] = Ps[g * 3 + 2] + F[g * 3 + 2];
        } else {
            qx[k] = Pd[g * 3 + 0]; qy[k] = Pd[g * 3 + 1]; qz[k] = Pd[g * 3 + 2];
        }
        bt[k] = -1e30f;
    }

#pragma unroll 4
    for (int j = 0; j < SPS; ++j) {
        const float4 s = sp[j];
#pragma unroll
        for (int k = 0; k < QPT; ++k) {
            float t = fmaf(qx[k], s.x, s.w);
            t = fmaf(qy[k], s.y, t);
            t = fmaf(qz[k], s.z, t);
            bt[k] = fmaxf(bt[k], t);
        }
    }

#pragma unroll
    for (int k = 0; k < QPT; ++k) {
        const int q = (b * 2 + dir) * NPTS + qc * QPB + k * BLK + tid;
        atomicMax(best + q, enc_f(bt[k]));
    }
}

// Kernel 2: decode best, d = |q|^2 - t (clamped at 0), mask + threshold,
// wave-reduce sum/count, atomicAdd into per-(b,dir) accumulators.
__global__ __launch_bounds__(BLK) void finalize_kernel(
    const float* __restrict__ Ps, const float* __restrict__ Pd,
    const float* __restrict__ F,  const int* __restrict__ Ms,
    const int* __restrict__ Md,   const unsigned* __restrict__ best,
    float* __restrict__ sums, float* __restrict__ cnts)
{
    const int b   = blockIdx.z;
    const int dir = blockIdx.y;
    const int q   = blockIdx.x * BLK + threadIdx.x;
    const int g   = b * NPTS + q;

    float x, y, z; int v;
    if (dir == 0) {
        x = Ps[g * 3 + 0] + F[g * 3 + 0];
        y = Ps[g * 3 + 1] + F[g * 3 + 1];
        z = Ps[g * 3 + 2] + F[g * 3 + 2];
        v = Ms[g];
    } else {
        x = Pd[g * 3 + 0]; y = Pd[g * 3 + 1]; z = Pd[g * 3 + 2];
        v = Md[g];
    }
    const float t = dec_f(best[(b * 2 + dir) * NPTS + q]);
    float d = fmaf(x, x, fmaf(y, y, z * z)) - t;
    d = fmaxf(d, 0.f);
    const bool sel = (v > 0) && (d < THR);
    float s = sel ? d : 0.f;
    float c = sel ? 1.f : 0.f;
#pragma unroll
    for (int off = 32; off; off >>= 1) {
        s += __shfl_down(s, off);
        c += __shfl_down(c, off);
    }
    if ((threadIdx.x & 63) == 0) {
        atomicAdd(&sums[b * 2 + dir], s);
        atomicAdd(&cnts[b * 2 + dir], c);
    }
}

// Kernel 3: out = sum over (b,dir) of sums/cnts
__global__ void reduce_out_kernel(const float* __restrict__ sums,
                                  const float* __restrict__ cnts,
                                  float* __restrict__ out)
{
    if (threadIdx.x == 0 && blockIdx.x == 0) {
        float a = 0.f;
#pragma unroll
        for (int i = 0; i < 2 * NB; ++i) a += sums[i] / cnts[i];
        out[0] = a;
    }
}

extern "C" void kernel_launch(void* const* d_in, const int* in_sizes, int n_in,
                              void* d_out, int out_size, void* d_ws, size_t ws_size,
                              hipStream_t stream)
{
    const float* Ps = (const float*)d_in[0];   // points_src  [B,N,3]
    const float* Pd = (const float*)d_in[1];   // points_dst  [B,N,3]
    const float* F  = (const float*)d_in[2];   // flows_pred  [B,N,3]
    // d_in[3] = flows_gt (unused by reference)
    const int* Ms = (const int*)d_in[4];       // masks_src [B,N]
    const int* Md = (const int*)d_in[5];       // masks_dst [B,N]
    float* out = (float*)d_out;

    unsigned* best = (unsigned*)d_ws;                       // B*2*N uints
    float* sums = (float*)((char*)d_ws + NB * 2 * NPTS * 4);
    float* cnts = sums + 2 * NB;

    const size_t clear_bytes = (size_t)NB * 2 * NPTS * 4 + 2 * NB * 4 * 2;
    hipMemsetAsync(d_ws, 0, clear_bytes, stream);

    dim3 g1(NQC * SS, 2, NB);
    knn_max_kernel<<<g1, BLK, 0, stream>>>(Ps, Pd, F, Ms, Md, best);

    dim3 g2(NPTS / BLK, 2, NB);
    finalize_kernel<<<g2, BLK, 0, stream>>>(Ps, Pd, F, Ms, Md, best, sums, cnts);

    reduce_out_kernel<<<1, 64, 0, stream>>>(sums, cnts, out);
}

// Round 2
// 62.364 us; speedup vs baseline: 1.3768x; 1.3768x over previous
//
#include <hip/hip_runtime.h>
#include <hip/hip_bf16.h>

#define NPTS 8192
#define NB   4
#define BLK  256
#define QPT  4
#define QPB  (QPT * BLK)          // 1024 queries per block
#define NQC_MAX (NPTS / QPB)      // 8 query chunks (capacity)
#define NSL  16                   // search slices (fixed count, dynamic length)
#define SLICE_MAX ((NPTS + NSL - 1) / NSL)   // 512 -> 8 KiB LDS max
#define CAP  NPTS
#define THR  3.33f

__device__ __forceinline__ unsigned enc_f(float f) {
    unsigned u = __float_as_uint(f);
    return (u & 0x80000000u) ? ~u : (u | 0x80000000u);
}
__device__ __forceinline__ float dec_f(unsigned u) {
    return (u & 0x80000000u) ? __uint_as_float(u & 0x7FFFFFFFu)
                             : __uint_as_float(~u);
}

// ---------------------------------------------------------------------------
// Kernel A: compact valid points per (batch, side).
// side 0 = warped src (Ps+F, mask Ms), side 1 = dst (Pd, mask Md).
// Stored encoded as (2x, 2y, 2z, -(x^2+y^2+z^2)).
// Per-wave coalesced atomicAdd append; order irrelevant (min/mean invariant).
// ---------------------------------------------------------------------------
__global__ __launch_bounds__(BLK) void compact_kernel(
    const float* __restrict__ Ps, const float* __restrict__ Pd,
    const float* __restrict__ F,  const int* __restrict__ Ms,
    const int* __restrict__ Md,   unsigned* __restrict__ counts,
    float4* __restrict__ pts)
{
    const int b = blockIdx.z, side = blockIdx.y;
    const int i = blockIdx.x * BLK + threadIdx.x;
    const int g = b * NPTS + i;
    float x, y, z; int v;
    if (side == 0) {
        x = Ps[3 * g + 0] + F[3 * g + 0];
        y = Ps[3 * g + 1] + F[3 * g + 1];
        z = Ps[3 * g + 2] + F[3 * g + 2];
        v = Ms[g];
    } else {
        x = Pd[3 * g + 0]; y = Pd[3 * g + 1]; z = Pd[3 * g + 2];
        v = Md[g];
    }
    if (v > 0) {
        unsigned pos = atomicAdd(&counts[b * 2 + side], 1u);
        pts[(size_t)(b * 2 + side) * CAP + pos] =
            make_float4(2.f * x, 2.f * y, 2.f * z, -(x * x + y * y + z * z));
    }
}

// ---------------------------------------------------------------------------
// Kernel B: for each (b,dir) the queries are side=dir, search set side=1-dir.
// max over search slice of t = 2*q.s - |s|^2 ; combine via atomicMax(enc).
// ---------------------------------------------------------------------------
__global__ __launch_bounds__(BLK) void knn_kernel(
    const unsigned* __restrict__ counts, const float4* __restrict__ pts,
    unsigned* __restrict__ best)
{
    const int b = blockIdx.z, d = blockIdx.y;
    const int qc = blockIdx.x / NSL, sl = blockIdx.x % NSL;
    const int qi = b * 2 + d;          // query side
    const int si = b * 2 + (1 - d);    // search side
    const int nq = (int)counts[qi];
    const int ns = (int)counts[si];
    if (qc * QPB >= nq) return;                       // uniform exit
    const int slice = (ns + NSL - 1) / NSL;
    const int start = sl * slice;
    int len = ns - start; if (len > slice) len = slice;
    if (len <= 0) return;                             // uniform exit

    __shared__ float4 sp[SLICE_MAX];
    const float4* __restrict__ sarr = pts + (size_t)si * CAP + start;
    for (int i = threadIdx.x; i < len; i += BLK) sp[i] = sarr[i];
    __syncthreads();

    const float4* __restrict__ qarr = pts + (size_t)qi * CAP;
    float qx[QPT], qy[QPT], qz[QPT], bt[QPT];
    int qn_[QPT]; bool qv[QPT];
#pragma unroll
    for (int k = 0; k < QPT; ++k) {
        const int q = qc * QPB + k * BLK + threadIdx.x;
        qn_[k] = q; qv[k] = (q < nq);
        float4 p = qarr[qv[k] ? q : 0];
        qx[k] = 0.5f * p.x; qy[k] = 0.5f * p.y; qz[k] = 0.5f * p.z;
        bt[k] = -1e30f;
    }

#pragma unroll 4
    for (int j = 0; j < len; ++j) {
        const float4 s = sp[j];           // wave-uniform -> LDS broadcast
#pragma unroll
        for (int k = 0; k < QPT; ++k) {
            float t = fmaf(qx[k], s.x, s.w);
            t = fmaf(qy[k], s.y, t);
            t = fmaf(qz[k], s.z, t);
            bt[k] = fmaxf(bt[k], t);
        }
    }

#pragma unroll
    for (int k = 0; k < QPT; ++k)
        if (qv[k]) atomicMax(&best[(size_t)qi * CAP + qn_[k]], enc_f(bt[k]));
}

// ---------------------------------------------------------------------------
// Kernel C: decode best, d = |q|^2 - t (clamped), threshold, wave-reduce.
// All compacted queries are valid, so selection is just d < THR.
// ---------------------------------------------------------------------------
__global__ __launch_bounds__(BLK) void finalize_kernel(
    const unsigned* __restrict__ counts, const float4* __restrict__ pts,
    const unsigned* __restrict__ best, float* __restrict__ sums,
    float* __restrict__ cnts)
{
    const int b = blockIdx.z, d = blockIdx.y;
    const int qi = b * 2 + d;
    const int q = blockIdx.x * BLK + threadIdx.x;
    const int nq = (int)counts[qi];
    float s = 0.f, c = 0.f;
    if (q < nq) {
        const float4 p = pts[(size_t)qi * CAP + q];
        const float t = dec_f(best[(size_t)qi * CAP + q]);
        float dd = (-p.w) - t;
        dd = fmaxf(dd, 0.f);
        if (dd < THR) { s = dd; c = 1.f; }
    }
#pragma unroll
    for (int off = 32; off; off >>= 1) {
        s += __shfl_down(s, off);
        c += __shfl_down(c, off);
    }
    if ((threadIdx.x & 63) == 0) {
        atomicAdd(&sums[qi], s);
        atomicAdd(&cnts[qi], c);
    }
}

__global__ void reduce_out_kernel(const float* __restrict__ sums,
                                  const float* __restrict__ cnts,
                                  float* __restrict__ out)
{
    if (threadIdx.x == 0 && blockIdx.x == 0) {
        float a = 0.f;
#pragma unroll
        for (int i = 0; i < 2 * NB; ++i) a += sums[i] / cnts[i];
        out[0] = a;
    }
}

extern "C" void kernel_launch(void* const* d_in, const int* in_sizes, int n_in,
                              void* d_out, int out_size, void* d_ws, size_t ws_size,
                              hipStream_t stream)
{
    const float* Ps = (const float*)d_in[0];   // points_src  [B,N,3]
    const float* Pd = (const float*)d_in[1];   // points_dst  [B,N,3]
    const float* F  = (const float*)d_in[2];   // flows_pred  [B,N,3]
    // d_in[3] = flows_gt (unused)
    const int* Ms = (const int*)d_in[4];       // masks_src [B,N]
    const int* Md = (const int*)d_in[5];       // masks_dst [B,N]
    float* out = (float*)d_out;

    // workspace layout:
    //   [0..32)        counts  (8 x u32)
    //   [32..64)       sums    (8 x f32)
    //   [64..96)       cnts    (8 x f32)
    //   [128..262272)  best    (8*CAP x u32)
    //   [262272..+1MB) pts     (8*CAP x float4)   total ~1.31 MB
    unsigned* counts = (unsigned*)d_ws;
    float* sums = (float*)((char*)d_ws + 32);
    float* cnts = (float*)((char*)d_ws + 64);
    unsigned* best = (unsigned*)((char*)d_ws + 128);
    float4* pts = (float4*)((char*)d_ws + 128 + (size_t)8 * CAP * 4);

    hipMemsetAsync(d_ws, 0, 128 + (size_t)8 * CAP * 4, stream);

    compact_kernel<<<dim3(NPTS / BLK, 2, NB), BLK, 0, stream>>>(
        Ps, Pd, F, Ms, Md, counts, pts);

    knn_kernel<<<dim3(NQC_MAX * NSL, 2, NB), BLK, 0, stream>>>(counts, pts, best);

    finalize_kernel<<<dim3(NPTS / BLK, 2, NB), BLK, 0, stream>>>(
        counts, pts, best, sums, cnts);

    reduce_out_kernel<<<1, 64, 0, stream>>>(sums, cnts, out);
}